// Round 2
// baseline (349.662 us; speedup 1.0000x reference)
//
#include <hip/hip_runtime.h>

#define RM_EPS 1e-10f

// 16 lanes per ray, 8 consecutive samples per lane, 4 rays per wave.
// Per-lane serial cumprod (VALU) + width-16 segmented shuffle scan/reduce.
__global__ __launch_bounds__(256) void raymarch_kernel(
    const float* __restrict__ dens,   // (n_rays, 128)
    const float* __restrict__ feat,   // (n_rays, 128, 3)
    const float* __restrict__ len,    // (n_rays, 128)
    float* __restrict__ out,          // (n_rays, 4)
    int n_rays)
{
    const int lane  = (int)(threadIdx.x & 63);
    const int gwave = (int)((blockIdx.x * blockDim.x + threadIdx.x) >> 6);
    const int rseg  = lane >> 4;      // which of the wave's 4 rays
    const int sl    = lane & 15;      // sub-lane within the ray's 16-lane segment
    const long long ray = (long long)gwave * 4 + rseg;
    if (ray >= n_rays) return;

    // Per-lane contiguous vector loads (32 B dens, 32 B len, 96 B feat)
    const float4* dp = (const float4*)(dens + ray * 128 + sl * 8);
    const float4* lp = (const float4*)(len  + ray * 128 + sl * 8);
    const float4* fp = (const float4*)(feat + ray * 384 + sl * 24);
    const float4 d0 = dp[0], d1 = dp[1];
    const float4 l0 = lp[0], l1 = lp[1];
    const float4 f0 = fp[0], f1 = fp[1], f2 = fp[2];
    const float4 f3 = fp[3], f4 = fp[4], f5 = fp[5];

    const float d[8]  = {d0.x,d0.y,d0.z,d0.w, d1.x,d1.y,d1.z,d1.w};
    const float ll[8] = {l0.x,l0.y,l0.z,l0.w, l1.x,l1.y,l1.z,l1.w};
    const float f[24] = {f0.x,f0.y,f0.z,f0.w, f1.x,f1.y,f1.z,f1.w,
                         f2.x,f2.y,f2.z,f2.w, f3.x,f3.y,f3.z,f3.w,
                         f4.x,f4.y,f4.z,f4.w, f5.x,f5.y,f5.z,f5.w};

    // Serial local product of absorption terms over this lane's 8 samples
    float cp = 1.0f;
    #pragma unroll
    for (int i = 0; i < 8; ++i) cp *= (1.0f + RM_EPS - d[i]);

    // Inclusive multiplicative scan across the 16-lane segment (4 steps)
    float p = cp;
    #pragma unroll
    for (int off = 1; off < 16; off <<= 1) {
        float q = __shfl_up(p, off, 16);
        if (sl >= off) p *= q;
    }
    // Exclusive prefix product = absorption before this lane's first sample
    float e = __shfl_up(p, 1, 16);
    if (sl == 0) e = 1.0f;

    // Serial weighted accumulation with running prefix
    float s0 = 0.f, s1 = 0.f, s2 = 0.f, sd = 0.f, sa = 0.f;
    float run = e;
    #pragma unroll
    for (int i = 0; i < 8; ++i) {
        const float wi = d[i] * run;
        s0 += wi * f[3*i+0];
        s1 += wi * f[3*i+1];
        s2 += wi * f[3*i+2];
        sd += wi * ll[i];
        sa += wi;
        run *= (1.0f + RM_EPS - d[i]);
    }

    // Width-16 butterfly reduction (4 levels x 5 values)
    #pragma unroll
    for (int off = 8; off > 0; off >>= 1) {
        s0 += __shfl_xor(s0, off, 16);
        s1 += __shfl_xor(s1, off, 16);
        s2 += __shfl_xor(s2, off, 16);
        sd += __shfl_xor(sd, off, 16);
        sa += __shfl_xor(sa, off, 16);
    }
    const float last_len = __shfl(l1.w, 15, 16);  // lengths[..., -1]

    if (sl == 0) {
        const float bg = 1.0f - sa;
        float4 o;
        o.x = s0 + bg;
        o.y = s1 + bg;
        o.z = s2 + bg;
        o.w = sd + bg * last_len;
        ((float4*)out)[ray] = o;
    }
}

extern "C" void kernel_launch(void* const* d_in, const int* in_sizes, int n_in,
                              void* d_out, int out_size, void* d_ws, size_t ws_size,
                              hipStream_t stream) {
    const float* dens = (const float*)d_in[0];  // rays_densities (B,R,N,1)
    const float* feat = (const float*)d_in[1];  // rays_features  (B,R,N,3)
    const float* len  = (const float*)d_in[2];  // lengths        (B,R,N)
    float* out = (float*)d_out;                 // (B,R,4)

    const int n_rays = in_sizes[0] / 128;       // B*R = 131072
    const long long waves = (n_rays + 3) / 4;   // 4 rays per wave
    const long long threads = waves * 64;
    const int block = 256;
    const int grid = (int)((threads + block - 1) / block);
    raymarch_kernel<<<grid, block, 0, stream>>>(dens, feat, len, out, n_rays);
}